// Round 6
// baseline (184.340 us; speedup 1.0000x reference)
//
#include <hip/hip_runtime.h>

// SWD18: per-feature cyclic window-of-5 sort (verified absmax=0 through R13):
// for column i, sort rows {5m + (i%5) + j mod L, j=0..4} ascending, in place.
// q, k are dead inputs.
//
// R13 post-mortem: asm value-pin changed NOTHING (dur 42.1 vs 42.6, VALU 24%,
// FETCH 32MB identical) and VGPR_Count=32 is impossible with 14 f4 provably
// live -> either the counter is quantized or the compiler built the pinned
// vectors from re-sunk scalar loads. Three rounds of IR-level hints (R6 array,
// R12 vec loads, R13 pin) all failed to change the load schedule. Little's
// law on measured 2.3 TB/s @ ~500cy latency => only ~4-5 1KB loads in flight
// PER CU (should be ~240): the machine code has ~1 load in flight per wave.
//
// R14: enforce batching at the only uncheatable layer - inline asm.
// 14x global_load_dwordx4 as volatile asm (the asm IS the load: cannot be
// scalarized, sunk, or interleaved with compute), one s_waitcnt vmcnt(0)
// wall + sched_barrier(0) (rule #18), then the verified COMP path unchanged.
// Decisive: if MLP was the limiter it now cannot be absent.
// Prediction: kernel 42 -> 15-20 us, VALUBusy -> 45-55%, bench ~157-163;
// if dur stays ~42, MLP theory is dead -> memory-system limit, A/B NT stores
// or LDS staging next.

constexpr int L   = 4000;
constexpr int D   = 512;
constexpr int NW  = L / 5;        // 800 windows per batch
constexpr int WPB = 2;            // windows per block
constexpr int NBX = NW / WPB;     // 400 blocks in x per batch

typedef float f4 __attribute__((ext_vector_type(4)));

// optimal 9-comparator sorting network for 5, ascending
#define CE(a, b) { float lo_ = fminf(a, b); float hi_ = fmaxf(a, b); (a) = lo_; (b) = hi_; }

__global__ __launch_bounds__(256, 4)
void swd18_asmld(const float* __restrict__ v, float* __restrict__ out) {
    // ---- bijective XCD-chunk swizzle (nwg = 3200, nwg%8 == 0 -> rm = 0) ----
    const int nwg = gridDim.x * gridDim.y;
    const int lid = blockIdx.x + gridDim.x * blockIdx.y;   // dispatch order
    const int qq  = nwg >> 3;
    const int xcd = lid & 7;
    const int pos = lid >> 3;
    const int nid = xcd * qq + pos;

    const int b  = nid / NBX;
    const int bx = nid % NBX;

    const int w  = WPB * bx + (threadIdx.x >> 7);  // window index (wave-uniform)
    const int q  = threadIdx.x & 127;              // column quad 0..127
    const int c0 = q << 2;                         // first column of quad
    const int R0 = 5 * w;                          // output rows R0..R0+4

    const f4* __restrict__ vb4 = (const f4*)(v   + (size_t)b * (L * D));
    f4*       __restrict__ ob4 = (f4*)      (out + (size_t)b * (L * D));

    // ---- 14 forced-in-flight dwordx4 loads: rows R0-5..R0+8 (1KB/wave-instr,
    // row wave-uniform, lanes contiguous 16B). Volatile asm = exact codegen:
    // 14 back-to-back global_load_dwordx4, one vmcnt wall, values resident.
    f4 in[14];
#pragma unroll
    for (int r = 0; r < 14; ++r) {
        int row = R0 - 5 + r;
        if (row < 0)  row += L;                    // w==0 wrap
        if (row >= L) row -= L;                    // w==NW-1 wrap
        const f4* p = vb4 + (size_t)row * (D / 4) + q;
        asm volatile("global_load_dwordx4 %0, %1, off"
                     : "=&v"(in[r]) : "v"(p));
    }
    asm volatile("s_waitcnt vmcnt(0)" ::: "memory");
    __builtin_amdgcn_sched_barrier(0);             // rule #18: no compute hoist

    const int rc0 = c0 % 5;
    f4 o0, o1, o2, o3, o4;

    // Per component: verified R7/R8 A/B window select + sorts + output mux.
    // p[n] == in[n].F ; out rows R0+t get (t < rc) ? A[t+5-rc] : B[t-rc].
#define COMP(J, F) do {                                                         \
    int rcj = rc0 + (J); if (rcj >= 5) rcj -= 5;                                \
    const bool e0 = rcj == 0, e1 = rcj == 1, e2 = rcj == 2, e3 = rcj == 3;      \
    float A0 = e0 ? in[0].F : e1 ? in[1].F : e2 ? in[2].F : e3 ? in[3].F : in[4].F;   \
    float A1 = e0 ? in[1].F : e1 ? in[2].F : e2 ? in[3].F : e3 ? in[4].F : in[5].F;   \
    float A2 = e0 ? in[2].F : e1 ? in[3].F : e2 ? in[4].F : e3 ? in[5].F : in[6].F;   \
    float A3 = e0 ? in[3].F : e1 ? in[4].F : e2 ? in[5].F : e3 ? in[6].F : in[7].F;   \
    float A4 = e0 ? in[4].F : e1 ? in[5].F : e2 ? in[6].F : e3 ? in[7].F : in[8].F;   \
    float B0 = e0 ? in[5].F : e1 ? in[6].F : e2 ? in[7].F : e3 ? in[8].F : in[9].F;   \
    float B1 = e0 ? in[6].F : e1 ? in[7].F : e2 ? in[8].F : e3 ? in[9].F : in[10].F;  \
    float B2 = e0 ? in[7].F : e1 ? in[8].F : e2 ? in[9].F : e3 ? in[10].F : in[11].F; \
    float B3 = e0 ? in[8].F : e1 ? in[9].F : e2 ? in[10].F : e3 ? in[11].F : in[12].F;\
    float B4 = e0 ? in[9].F : e1 ? in[10].F : e2 ? in[11].F : e3 ? in[12].F : in[13].F;\
    CE(A0, A1) CE(A3, A4) CE(A2, A4) CE(A2, A3) CE(A1, A4)                      \
    CE(A0, A3) CE(A0, A2) CE(A1, A3) CE(A1, A2)                                 \
    CE(B0, B1) CE(B3, B4) CE(B2, B4) CE(B2, B3) CE(B1, B4)                      \
    CE(B0, B3) CE(B0, B2) CE(B1, B3) CE(B1, B2)                                 \
    o0.F = e0 ? B0 : e1 ? A4 : e2 ? A3 : e3 ? A2 : A1;                          \
    o1.F = e0 ? B1 : e1 ? B0 : e2 ? A4 : e3 ? A3 : A2;                          \
    o2.F = e0 ? B2 : e1 ? B1 : e2 ? B0 : e3 ? A4 : A3;                          \
    o3.F = e0 ? B3 : e1 ? B2 : e2 ? B1 : e3 ? B0 : A4;                          \
    o4.F = e0 ? B4 : e1 ? B3 : e2 ? B2 : e3 ? B1 : B0;                          \
} while (0)

    COMP(0, x);
    COMP(1, y);
    COMP(2, z);
    COMP(3, w);
#undef COMP

    // ---- 5 f4 NT stores: rows R0..R0+4 (never wrap), 1KB/wave-instr ----
    f4* o = ob4 + (size_t)R0 * (D / 4) + q;
    __builtin_nontemporal_store(o0, o + 0 * (D / 4));
    __builtin_nontemporal_store(o1, o + 1 * (D / 4));
    __builtin_nontemporal_store(o2, o + 2 * (D / 4));
    __builtin_nontemporal_store(o3, o + 3 * (D / 4));
    __builtin_nontemporal_store(o4, o + 4 * (D / 4));
}

#undef CE

extern "C" void kernel_launch(void* const* d_in, const int* in_sizes, int n_in,
                              void* d_out, int out_size, void* d_ws, size_t ws_size,
                              hipStream_t stream) {
    // setup_inputs order: q, k, v — only v is used by the reference forward.
    const float* v = (const float*)d_in[2];
    float* out = (float*)d_out;

    const int B = in_sizes[2] / (L * D);           // 8 for the bench shape
    dim3 grid(NBX, B);                             // 400 x 8 = 3200 blocks of 256
    swd18_asmld<<<grid, dim3(256), 0, stream>>>(v, out);
}

// Round 7
// 177.010 us; speedup vs baseline: 1.0414x; 1.0414x over previous
//
#include <hip/hip_runtime.h>

// SWD18: per-feature cyclic window-of-5 sort (verified absmax=0 through R14):
// for column i, sort rows {5m + (i%5) + j mod L, j=0..4} ascending, in place.
// q, k are dead inputs.
//
// R14 post-mortem: 14 asm-batched loads + vmcnt(0) wall -> dur UNCHANGED
// (43.5 us). MLP theory dead. Unified model that fits R12/R13/R14 exactly:
// LOGICAL traffic (L3-served reads included) streams at ~5.6 TB/s ~= 89% of
// the m13 copy ceiling; 243 MB logical (2.8x read amp + 64 MB writes) /
// 5.6 TB/s = 43.4 us. L3 hits are not fast on this part; the kernel was
// already at the memory-system roofline FOR ITS TRAFFIC. The only lever is
// cutting amplification.
//
// R15: R14's proven skeleton (upfront volatile-asm loads -> one vmcnt(0)
// wall -> verified COMP -> NT stores; no counted waits, spill-safe), scaled
// to amp 1.36x: thread = (strip of G=5 windows, f2 column). 34 upfront
// global_load_dwordx2 (rows R0-5..R0+28 = union of the five verified 14-row
// footprints; window k uses in[5k..5k+13], identical algebra), 25 f2 NT
// stores. Traffic 243 -> 151 MB. Grid 160x8 = 1280 blocks = 5/CU exact;
// ~80 live VGPR under the 128 cap of __launch_bounds__(256,4).
// Prediction: kernel 43.5 -> 27-31 us, bench ~168-173, absmax 0.
// If dur ~43 again: traffic model wrong -> A/B NT stores next.

constexpr int L    = 4000;
constexpr int D    = 512;
constexpr int G    = 5;            // windows per strip (per thread)
constexpr int SR   = 5 * G;        // 25 output rows per strip
constexpr int NSTR = L / SR;       // 160 strips per batch
constexpr int NR   = SR + 9;       // 34 rows loaded: R0-5 .. R0+28

typedef float f2 __attribute__((ext_vector_type(2)));

// optimal 9-comparator sorting network for 5, ascending
#define CE(a, b) { float lo_ = fminf(a, b); float hi_ = fmaxf(a, b); (a) = lo_; (b) = hi_; }

__global__ __launch_bounds__(256, 4)
void swd18_f2g5(const float* __restrict__ v, float* __restrict__ out) {
    // ---- bijective XCD-chunk swizzle (nwg = 1280, 1280 % 8 == 0) ----
    const int nwg = gridDim.x * gridDim.y;
    const int lid = blockIdx.x + gridDim.x * blockIdx.y;   // dispatch order
    const int qq  = nwg >> 3;
    const int xcd = lid & 7;
    const int pos = lid >> 3;
    const int nid = xcd * qq + pos;        // XCD x owns batch x's strips contiguously

    const int b     = nid / NSTR;
    const int strip = nid % NSTR;
    const int t     = threadIdx.x;         // f2 column 0..255 (covers D=512)
    const int R0    = strip * SR;          // first output row of the strip

    const f2* __restrict__ vb2 = (const f2*)(v   + (size_t)b * (L * D));
    f2*       __restrict__ ob2 = (f2*)      (out + (size_t)b * (L * D));

    // ---- 34 upfront asm dwordx2 loads: rows R0-5..R0+28, 512B/wave-instr.
    // Volatile asm = exact codegen; cannot be scalarized or sunk (R14-proven).
    f2 in[NR];
#pragma unroll
    for (int r = 0; r < NR; ++r) {
        int row = R0 - 5 + r;
        if (row < 0)  row += L;            // strip 0 wraps at the top
        if (row >= L) row -= L;            // last strip wraps at the bottom
        const f2* p = vb2 + (size_t)row * (D / 2) + t;
        asm volatile("global_load_dwordx2 %0, %1, off"
                     : "=&v"(in[r]) : "v"(p));
    }
    asm volatile("s_waitcnt vmcnt(0)" ::: "memory");
    __builtin_amdgcn_sched_barrier(0);     // rule #18: no compute hoist

    const int rc0 = (2 * t) % 5;

    // Per component: verified R7..R14 A/B window select + sorts + output mux.
    // Window k (k=0..4): p[n] == in[5k+n].F ; out rows R0+5k+t get
    // (t < rc) ? A[t+5-rc] : B[t-rc].
#define COMP(WB, J, F) do {                                                     \
    int rcj = rc0 + (J); if (rcj >= 5) rcj -= 5;                                \
    const bool e0 = rcj == 0, e1 = rcj == 1, e2 = rcj == 2, e3 = rcj == 3;      \
    float A0 = e0 ? in[(WB)+0].F : e1 ? in[(WB)+1].F : e2 ? in[(WB)+2].F : e3 ? in[(WB)+3].F : in[(WB)+4].F;    \
    float A1 = e0 ? in[(WB)+1].F : e1 ? in[(WB)+2].F : e2 ? in[(WB)+3].F : e3 ? in[(WB)+4].F : in[(WB)+5].F;    \
    float A2 = e0 ? in[(WB)+2].F : e1 ? in[(WB)+3].F : e2 ? in[(WB)+4].F : e3 ? in[(WB)+5].F : in[(WB)+6].F;    \
    float A3 = e0 ? in[(WB)+3].F : e1 ? in[(WB)+4].F : e2 ? in[(WB)+5].F : e3 ? in[(WB)+6].F : in[(WB)+7].F;    \
    float A4 = e0 ? in[(WB)+4].F : e1 ? in[(WB)+5].F : e2 ? in[(WB)+6].F : e3 ? in[(WB)+7].F : in[(WB)+8].F;    \
    float B0 = e0 ? in[(WB)+5].F : e1 ? in[(WB)+6].F : e2 ? in[(WB)+7].F : e3 ? in[(WB)+8].F : in[(WB)+9].F;    \
    float B1 = e0 ? in[(WB)+6].F : e1 ? in[(WB)+7].F : e2 ? in[(WB)+8].F : e3 ? in[(WB)+9].F : in[(WB)+10].F;   \
    float B2 = e0 ? in[(WB)+7].F : e1 ? in[(WB)+8].F : e2 ? in[(WB)+9].F : e3 ? in[(WB)+10].F : in[(WB)+11].F;  \
    float B3 = e0 ? in[(WB)+8].F : e1 ? in[(WB)+9].F : e2 ? in[(WB)+10].F : e3 ? in[(WB)+11].F : in[(WB)+12].F; \
    float B4 = e0 ? in[(WB)+9].F : e1 ? in[(WB)+10].F : e2 ? in[(WB)+11].F : e3 ? in[(WB)+12].F : in[(WB)+13].F;\
    CE(A0, A1) CE(A3, A4) CE(A2, A4) CE(A2, A3) CE(A1, A4)                      \
    CE(A0, A3) CE(A0, A2) CE(A1, A3) CE(A1, A2)                                 \
    CE(B0, B1) CE(B3, B4) CE(B2, B4) CE(B2, B3) CE(B1, B4)                      \
    CE(B0, B3) CE(B0, B2) CE(B1, B3) CE(B1, B2)                                 \
    o0.F = e0 ? B0 : e1 ? A4 : e2 ? A3 : e3 ? A2 : A1;                          \
    o1.F = e0 ? B1 : e1 ? B0 : e2 ? A4 : e3 ? A3 : A2;                          \
    o2.F = e0 ? B2 : e1 ? B1 : e2 ? B0 : e3 ? A4 : A3;                          \
    o3.F = e0 ? B3 : e1 ? B2 : e2 ? B1 : e3 ? B0 : A4;                          \
    o4.F = e0 ? B4 : e1 ? B3 : e2 ? B2 : e3 ? B1 : B0;                          \
} while (0)

#pragma unroll
    for (int k = 0; k < G; ++k) {          // fully unrolled: in[] indices const
        f2 o0, o1, o2, o3, o4;
        COMP(5 * k, 0, x);
        COMP(5 * k, 1, y);

        // 5 f2 NT stores: rows R0+5k..R0+5k+4 (never wrap), 512B/wave-instr
        f2* o = ob2 + (size_t)(R0 + 5 * k) * (D / 2) + t;
        __builtin_nontemporal_store(o0, o + 0 * (D / 2));
        __builtin_nontemporal_store(o1, o + 1 * (D / 2));
        __builtin_nontemporal_store(o2, o + 2 * (D / 2));
        __builtin_nontemporal_store(o3, o + 3 * (D / 2));
        __builtin_nontemporal_store(o4, o + 4 * (D / 2));
    }
#undef COMP
}

#undef CE

extern "C" void kernel_launch(void* const* d_in, const int* in_sizes, int n_in,
                              void* d_out, int out_size, void* d_ws, size_t ws_size,
                              hipStream_t stream) {
    // setup_inputs order: q, k, v — only v is used by the reference forward.
    const float* v = (const float*)d_in[2];
    float* out = (float*)d_out;

    const int B = in_sizes[2] / (L * D);           // 8 for the bench shape
    dim3 grid(NSTR, B);                            // 160 x 8 = 1280 blocks of 256
    swd18_f2g5<<<grid, dim3(256), 0, stream>>>(v, out);
}